// Round 1
// baseline (143.077 us; speedup 1.0000x reference)
//
#include <hip/hip_runtime.h>

// AffinitySideLoss: B=4, E=12, H=W=512, S=8 offsets, output = 1 float scalar.
// d_in[0] = input_ float32 [4,12,512,512]
// d_in[1] = target int32   [4,1,512,512]
// d_in[2] = offsets int32  [8,2]  (values in [-27,0))
// d_out   = float32 [1]
// d_ws    = per-block partials: float [24][1024]  (98,304 B)

typedef float f4  __attribute__((ext_vector_type(4)));
typedef float f4u __attribute__((ext_vector_type(4), aligned(4)));
typedef int   i4  __attribute__((ext_vector_type(4)));
typedef int   i4u __attribute__((ext_vector_type(4), aligned(4)));

#define HWSZ 262144   // 512*512
#define NE   12
#define NS   8
#define NBLK 1024     // 262144 thread-groups / 256

__global__ __launch_bounds__(256) void affloss_main(
    const float* __restrict__ emb, const int* __restrict__ seg,
    const int* __restrict__ offs, float* __restrict__ partial) {
  __shared__ int soff[2 * NS];
  if (threadIdx.x < 2 * NS) soff[threadIdx.x] = offs[threadIdx.x];
  __syncthreads();

  const int g  = blockIdx.x * 256 + threadIdx.x;   // 0..262143
  const int w4 = (g & 127) << 2;                   // 0..508 step 4
  const int h  = (g >> 7) & 511;
  const int b  = g >> 16;

  const float* embB = emb + (size_t)b * NE * HWSZ;
  const int*   segB = seg + (size_t)b * HWSZ;
  const int base = (h << 9) + w4;

  // center embedding: 12 x float4 (aligned)
  f4 c[NE];
  #pragma unroll
  for (int e = 0; e < NE; ++e)
    c[e] = *reinterpret_cast<const f4*>(embB + e * HWSZ + base);
  const i4 tc = *reinterpret_cast<const i4*>(segB + base);

  float num[NS], da[NS], dt[NS];
  #pragma unroll
  for (int s = 0; s < NS; ++s) { num[s] = 0.f; da[s] = 0.f; dt[s] = 0.f; }

  #pragma unroll
  for (int s = 0; s < NS; ++s) {
    const int oy = soff[2 * s], ox = soff[2 * s + 1];
    int hs = h + oy; hs = hs < 0 ? 0 : (hs > 511 ? 511 : hs);
    const int rowoff = hs << 9;
    const int wsb = w4 + ox;

    f4 ssv = {0.f, 0.f, 0.f, 0.f};
    i4 ts;
    if (wsb >= 0 && wsb + 3 <= 511) {
      // interior: contiguous (possibly 4B-aligned-only) vector loads
      #pragma unroll
      for (int e = 0; e < NE; ++e) {
        f4 sh = *reinterpret_cast<const f4u*>(embB + e * HWSZ + rowoff + wsb);
        f4 d = c[e] - sh;
        ssv += d * d;
      }
      ts = *reinterpret_cast<const i4u*>(segB + rowoff + wsb);
    } else {
      // border: per-element replication clamp
      int w0 = wsb, w1 = wsb + 1, w2 = wsb + 2, w3 = wsb + 3;
      w0 = min(max(w0, 0), 511); w1 = min(max(w1, 0), 511);
      w2 = min(max(w2, 0), 511); w3 = min(max(w3, 0), 511);
      #pragma unroll
      for (int e = 0; e < NE; ++e) {
        const float* p = embB + e * HWSZ + rowoff;
        f4 sh = { p[w0], p[w1], p[w2], p[w3] };
        f4 d = c[e] - sh;
        ssv += d * d;
      }
      const int* ps = segB + rowoff;
      ts[0] = ps[w0]; ts[1] = ps[w1]; ts[2] = ps[w2]; ts[3] = ps[w3];
    }

    #pragma unroll
    for (int j = 0; j < 4; ++j) {
      float ss = ssv[j];
      float n  = ss > 0.f ? sqrtf(ss) : 0.f;      // matches where(ss>0, sqrt, 0)
      float r  = (3.0f - n) / 3.0f;               // (2*DELTA - norm)/(2*DELTA)
      r = fmaxf(r, 0.f);                          // clip(lower=0 only)
      float a  = 1.f - r * r;                     // affs = 1 - clip(...)^2
      float ta = (tc[j] == ts[j]) ? 0.f : 1.f;    // 1 - equality
      num[s] += a * ta;
      da[s]  += a * a;
      dt[s]  += ta;                               // ta^2 == ta
    }
  }

  // pack per-thread partials: [0..7]=num, [8..15]=sum a^2, [16..23]=sum ta
  float arr[24];
  #pragma unroll
  for (int s = 0; s < NS; ++s) { arr[s] = num[s]; arr[8 + s] = da[s]; arr[16 + s] = dt[s]; }

  // wave (64-lane) shuffle reduction per channel
  #pragma unroll
  for (int k = 0; k < 24; ++k) {
    float v = arr[k];
    #pragma unroll
    for (int o = 32; o > 0; o >>= 1) v += __shfl_down(v, o, 64);
    arr[k] = v;
  }

  __shared__ float red[4][24];
  const int lane = threadIdx.x & 63, wv = threadIdx.x >> 6;
  if (lane == 0) {
    #pragma unroll
    for (int k = 0; k < 24; ++k) red[wv][k] = arr[k];
  }
  __syncthreads();
  if (threadIdx.x < 24) {
    float v = red[0][threadIdx.x] + red[1][threadIdx.x] +
              red[2][threadIdx.x] + red[3][threadIdx.x];
    partial[threadIdx.x * NBLK + blockIdx.x] = v;   // [channel][block], coalesced for K2
  }
}

__global__ __launch_bounds__(256) void affloss_final(
    const float* __restrict__ partial, float* __restrict__ out) {
  __shared__ double csum[24];
  const int lane = threadIdx.x & 63, wv = threadIdx.x >> 6;

  for (int c = wv; c < 24; c += 4) {
    double s = 0.0;
    for (int i = lane; i < NBLK; i += 64)
      s += (double)partial[c * NBLK + i];
    #pragma unroll
    for (int o = 32; o > 0; o >>= 1) s += __shfl_down(s, o, 64);
    if (lane == 0) csum[c] = s;
  }
  __syncthreads();

  if (threadIdx.x == 0) {
    double total = 0.0;
    #pragma unroll
    for (int c = 0; c < 8; ++c) {
      double num = csum[c];
      double den = csum[8 + c] + csum[16 + c];
      if (den < 1e-7) den = 1e-7;                 // maximum(den, EPS); den ~2e6 >> EPS
      total += 1.0 - 2.0 * num / den;
    }
    out[0] = (float)total;
  }
}

extern "C" void kernel_launch(void* const* d_in, const int* in_sizes, int n_in,
                              void* d_out, int out_size, void* d_ws, size_t ws_size,
                              hipStream_t stream) {
  const float* emb  = (const float*)d_in[0];
  const int*   seg  = (const int*)d_in[1];
  const int*   offs = (const int*)d_in[2];
  float* partial = (float*)d_ws;   // 24*1024 floats = 98,304 B

  affloss_main<<<NBLK, 256, 0, stream>>>(emb, seg, offs, partial);
  affloss_final<<<1, 256, 0, stream>>>(partial, (float*)d_out);
}

// Round 2
// 55.854 us; speedup vs baseline: 2.5616x; 2.5616x over previous
//
#include <hip/hip_runtime.h>

// AffinitySideLoss: B=4, E=12, H=W=512, S=8 offsets, output = 1 float scalar.
// d_in[0] = input_ float32 [4,12,512,512]
// d_in[1] = target int32   [4,1,512,512]
// d_in[2] = offsets int32  [8,2]  (values in [-27,0))
// d_out   = float32 [1]
// d_ws    = per-block partials: float [16][2048]  (131,072 B)

typedef float f2  __attribute__((ext_vector_type(2)));
typedef float f2u __attribute__((ext_vector_type(2), aligned(4)));
typedef int   i2  __attribute__((ext_vector_type(2)));
typedef int   i2u __attribute__((ext_vector_type(2), aligned(4)));

#define HWSZ 262144   // 512*512
#define NE   12
#define NS   8
#define NBLK 2048     // one block per image row (4 batches x 512 rows)

__global__ __launch_bounds__(256) void affloss_main(
    const float* __restrict__ emb, const int* __restrict__ seg,
    const int* __restrict__ offs, float* __restrict__ partial) {
  __shared__ int soff[2 * NS];
  if (threadIdx.x < 2 * NS) soff[threadIdx.x] = offs[threadIdx.x];
  __syncthreads();

  // XCD-aware swizzle: 2048 blocks % 8 == 0 -> each XCD gets a contiguous
  // 256-row band. Shifted rows (up to 27 above) were recent center rows of
  // neighbor blocks on the SAME XCD -> L2 hits instead of HBM refetch.
  const int bid = blockIdx.x;
  const int nb  = (bid & 7) * (NBLK / 8) + (bid >> 3);

  const int g  = nb * 256 + threadIdx.x;           // 0..524287, 2 px each
  const int w2 = (g & 255) << 1;                   // 0..510 step 2
  const int h  = nb & 511;
  const int b  = nb >> 9;

  const float* embB = emb + (size_t)b * NE * HWSZ;
  const int*   segB = seg + (size_t)b * HWSZ;
  const int base = (h << 9) + w2;

  // center embedding: 12 x float2 (8B aligned)
  f2 c[NE];
  #pragma unroll
  for (int e = 0; e < NE; ++e)
    c[e] = *reinterpret_cast<const f2*>(embB + e * HWSZ + base);
  const i2 tc = *reinterpret_cast<const i2*>(segB + base);

  float num[NS], den[NS];
  #pragma unroll
  for (int s = 0; s < NS; ++s) { num[s] = 0.f; den[s] = 0.f; }

  #pragma unroll
  for (int s = 0; s < NS; ++s) {
    const int oy = soff[2 * s], ox = soff[2 * s + 1];
    int hs = h + oy; hs = hs < 0 ? 0 : hs;         // oy < 0, no upper clamp needed
    const int rowoff = hs << 9;
    const int wsb = w2 + ox;                       // ox in [-27,-1]

    f2 ssv = {0.f, 0.f};
    i2 ts;
    if (wsb >= 0) {
      // interior: contiguous (4B-aligned) vector loads; wsb+1 <= 510 always
      #pragma unroll
      for (int e = 0; e < NE; ++e) {
        f2 sh = *reinterpret_cast<const f2u*>(embB + e * HWSZ + rowoff + wsb);
        f2 d = c[e] - sh;
        ssv += d * d;
      }
      ts = *reinterpret_cast<const i2u*>(segB + rowoff + wsb);
    } else {
      // border: per-element replication clamp (left edge only)
      int w0 = max(wsb, 0), w1 = max(wsb + 1, 0);
      #pragma unroll
      for (int e = 0; e < NE; ++e) {
        const float* p = embB + e * HWSZ + rowoff;
        f2 sh = { p[w0], p[w1] };
        f2 d = c[e] - sh;
        ssv += d * d;
      }
      const int* ps = segB + rowoff;
      ts[0] = ps[w0]; ts[1] = ps[w1];
    }

    #pragma unroll
    for (int j = 0; j < 2; ++j) {
      float ss = ssv[j];
      float n  = ss > 0.f ? sqrtf(ss) : 0.f;      // where(ss>0, sqrt, 0)
      float r  = (3.0f - n) / 3.0f;               // (2*DELTA - norm)/(2*DELTA)
      r = fmaxf(r, 0.f);                          // clip(lower=0)
      float a  = 1.f - r * r;                     // affinity
      float ta = (tc[j] == ts[j]) ? 0.f : 1.f;    // 1 - equality
      num[s] += a * ta;
      den[s] += a * a + ta;                       // ta^2 == ta
    }
  }

  // pack: [0..7]=num, [8..15]=den
  float arr[16];
  #pragma unroll
  for (int s = 0; s < NS; ++s) { arr[s] = num[s]; arr[8 + s] = den[s]; }

  // wave (64-lane) shuffle reduction per channel
  #pragma unroll
  for (int k = 0; k < 16; ++k) {
    float v = arr[k];
    #pragma unroll
    for (int o = 32; o > 0; o >>= 1) v += __shfl_down(v, o, 64);
    arr[k] = v;
  }

  __shared__ float red[4][16];
  const int lane = threadIdx.x & 63, wv = threadIdx.x >> 6;
  if (lane == 0) {
    #pragma unroll
    for (int k = 0; k < 16; ++k) red[wv][k] = arr[k];
  }
  __syncthreads();
  if (threadIdx.x < 16) {
    float v = red[0][threadIdx.x] + red[1][threadIdx.x] +
              red[2][threadIdx.x] + red[3][threadIdx.x];
    partial[threadIdx.x * NBLK + blockIdx.x] = v;  // [channel][block]
  }
}

__global__ __launch_bounds__(1024) void affloss_final(
    const float* __restrict__ partial, float* __restrict__ out) {
  __shared__ double csum[16];
  const int lane = threadIdx.x & 63, wv = threadIdx.x >> 6;  // wv = channel 0..15

  double s = 0.0;
  for (int i = lane; i < NBLK; i += 64)
    s += (double)partial[wv * NBLK + i];
  #pragma unroll
  for (int o = 32; o > 0; o >>= 1) s += __shfl_down(s, o, 64);
  if (lane == 0) csum[wv] = s;
  __syncthreads();

  if (threadIdx.x == 0) {
    double total = 0.0;
    #pragma unroll
    for (int c = 0; c < 8; ++c) {
      double num = csum[c];
      double den = csum[8 + c];
      if (den < 1e-7) den = 1e-7;                 // maximum(den, EPS)
      total += 1.0 - 2.0 * num / den;
    }
    out[0] = (float)total;
  }
}

extern "C" void kernel_launch(void* const* d_in, const int* in_sizes, int n_in,
                              void* d_out, int out_size, void* d_ws, size_t ws_size,
                              hipStream_t stream) {
  const float* emb  = (const float*)d_in[0];
  const int*   seg  = (const int*)d_in[1];
  const int*   offs = (const int*)d_in[2];
  float* partial = (float*)d_ws;   // 16*2048 floats = 131,072 B

  affloss_main<<<NBLK, 256, 0, stream>>>(emb, seg, offs, partial);
  affloss_final<<<1, 1024, 0, stream>>>(partial, (float*)d_out);
}

// Round 4
// 53.387 us; speedup vs baseline: 2.6800x; 1.0462x over previous
//
#include <hip/hip_runtime.h>

// AffinitySideLoss: B=4, E=12, H=W=512, S=8 offsets, output = 1 float scalar.
// d_in[0] = input_ float32 [4,12,512,512]
// d_in[1] = target int32   [4,1,512,512]
// d_in[2] = offsets int32  [8,2]  (values in [-27,0))
// d_out   = float32 [1]
// d_ws    = per-block partials: float [16][2048]  (131,072 B)
//
// Decomposition: one block per image row. nb in [0,2048): b = nb>>9 (0..3),
// h = nb&511. 256 threads x 2 px (float2): w2 = tid*2 in {0..510}.
// All of {b, h, oy, ox} are block-uniform and compiler-provably scalar
// (offsets read at uniform addresses -> s_load), so shifted-load addresses
// are SGPR-base + small VGPR offset.

typedef float f2  __attribute__((ext_vector_type(2)));
typedef float f2u __attribute__((ext_vector_type(2), aligned(4)));
typedef int   i2  __attribute__((ext_vector_type(2)));
typedef int   i2u __attribute__((ext_vector_type(2), aligned(4)));

#define HWSZ 262144   // 512*512
#define NE   12
#define NS   8
#define NBLK 2048     // 4 batches x 512 rows

__global__ __launch_bounds__(256) void affloss_main(
    const float* __restrict__ emb, const int* __restrict__ seg,
    const int* __restrict__ offs, float* __restrict__ partial) {
  // XCD-aware swizzle (bijective: 2048 % 8 == 0): contiguous 256-row band
  // per XCD so shifted rows (<=27 above) hit that XCD's L2.
  const int bid = blockIdx.x;
  const int nb  = (bid & 7) * (NBLK / 8) + (bid >> 3);

  const int h  = nb & 511;        // row, block-uniform
  const int b  = nb >> 9;         // batch 0..3, block-uniform
  const int w2 = threadIdx.x << 1; // 0..510

  const float* embB = emb + (size_t)b * NE * HWSZ;
  const int*   segB = seg + (size_t)b * HWSZ;
  const int base = (h << 9) + w2;

  // center embedding: 12 x float2 (8B aligned)
  f2 c[NE];
  #pragma unroll
  for (int e = 0; e < NE; ++e)
    c[e] = *reinterpret_cast<const f2*>(embB + e * HWSZ + base);
  const i2 tc = *reinterpret_cast<const i2*>(segB + base);

  float num[NS], den[NS];
  #pragma unroll
  for (int s = 0; s < NS; ++s) { num[s] = 0.f; den[s] = 0.f; }

  #pragma unroll
  for (int s = 0; s < NS; ++s) {
    // uniform-address loads -> scalar (s_load); oy,ox in [-27,-1]
    const int oy = offs[2 * s];
    const int ox = offs[2 * s + 1];
    int hs = h + oy; hs = hs < 0 ? 0 : hs;   // replication clamp (top only)
    const int rowoff = hs << 9;
    const int wsb = w2 + ox;                 // >= -27, <= 509

    f2 ssv = {0.f, 0.f};
    i2 ts;
    if (wsb >= 0) {
      #pragma unroll
      for (int e = 0; e < NE; ++e) {
        f2 sh = *reinterpret_cast<const f2u*>(embB + e * HWSZ + rowoff + wsb);
        f2 d = c[e] - sh;
        ssv += d * d;
      }
      ts = *reinterpret_cast<const i2u*>(segB + rowoff + wsb);
    } else {
      // left-edge replication clamp; only lanes with w2 < 27 take this
      int w0 = max(wsb, 0), w1 = max(wsb + 1, 0);
      #pragma unroll
      for (int e = 0; e < NE; ++e) {
        const float* p = embB + e * HWSZ + rowoff;
        f2 sh = { p[w0], p[w1] };
        f2 d = c[e] - sh;
        ssv += d * d;
      }
      const int* ps = segB + rowoff;
      ts[0] = ps[w0]; ts[1] = ps[w1];
    }

    #pragma unroll
    for (int j = 0; j < 2; ++j) {
      float ss = ssv[j];                       // >= 0 by construction
      float n  = __builtin_amdgcn_sqrtf(ss);   // v_sqrt_f32; sqrt(0)=0 covers where()
      float r  = fmaxf(fmaf(n, -(1.0f / 3.0f), 1.0f), 0.0f); // clip((3-n)/3, 0)
      float a  = fmaf(-r, r, 1.0f);            // affinity = 1 - r^2
      float ta = (tc[j] == ts[j]) ? 0.f : 1.f; // 1 - equality
      num[s] = fmaf(a, ta, num[s]);
      den[s] += fmaf(a, a, ta);                // a^2 + ta  (ta^2 == ta)
    }
  }

  // pack: [0..7]=num, [8..15]=den
  float arr[16];
  #pragma unroll
  for (int s = 0; s < NS; ++s) { arr[s] = num[s]; arr[8 + s] = den[s]; }

  // wave (64-lane) shuffle reduction per channel
  #pragma unroll
  for (int k = 0; k < 16; ++k) {
    float v = arr[k];
    #pragma unroll
    for (int o = 32; o > 0; o >>= 1) v += __shfl_down(v, o, 64);
    arr[k] = v;
  }

  __shared__ float red[4][16];
  const int lane = threadIdx.x & 63, wv = threadIdx.x >> 6;
  if (lane == 0) {
    #pragma unroll
    for (int k = 0; k < 16; ++k) red[wv][k] = arr[k];
  }
  __syncthreads();
  if (threadIdx.x < 16) {
    float v = red[0][threadIdx.x] + red[1][threadIdx.x] +
              red[2][threadIdx.x] + red[3][threadIdx.x];
    partial[threadIdx.x * NBLK + blockIdx.x] = v;  // [channel][block]
  }
}

__global__ __launch_bounds__(1024) void affloss_final(
    const float* __restrict__ partial, float* __restrict__ out) {
  __shared__ double csum[16];
  const int lane = threadIdx.x & 63, wv = threadIdx.x >> 6;  // wv = channel 0..15

  double s = 0.0;
  for (int i = lane; i < NBLK; i += 64)
    s += (double)partial[wv * NBLK + i];
  #pragma unroll
  for (int o = 32; o > 0; o >>= 1) s += __shfl_down(s, o, 64);
  if (lane == 0) csum[wv] = s;
  __syncthreads();

  if (threadIdx.x == 0) {
    double total = 0.0;
    #pragma unroll
    for (int c = 0; c < 8; ++c) {
      double num = csum[c];
      double den = csum[8 + c];
      if (den < 1e-7) den = 1e-7;              // maximum(den, EPS)
      total += 1.0 - 2.0 * num / den;
    }
    out[0] = (float)total;
  }
}

extern "C" void kernel_launch(void* const* d_in, const int* in_sizes, int n_in,
                              void* d_out, int out_size, void* d_ws, size_t ws_size,
                              hipStream_t stream) {
  const float* emb  = (const float*)d_in[0];
  const int*   seg  = (const int*)d_in[1];
  const int*   offs = (const int*)d_in[2];
  float* partial = (float*)d_ws;   // 16*2048 floats = 131,072 B

  affloss_main<<<NBLK, 256, 0, stream>>>(emb, seg, offs, partial);
  affloss_final<<<1, 1024, 0, stream>>>(partial, (float*)d_out);
}